// Round 21
// baseline (1381.696 us; speedup 1.0000x reference)
//
#include <hip/hip_runtime.h>
#include <math.h>

// Problem constants
#define F_DIM 321
#define H_DIM 4200
#define T_DIM 1000
#define NBC   16      // B*C = 8*2
#define KTOP  3
#define PADV  1e-8f

// r21: operand-bandwidth roofline fix. r12-r20 (9 variants) all pinned at
// VALUBusy 31-42% regardless of staging/sync/occupancy. Invariant: B-operand
// delivery = 256/R bytes per FMA-inst; at R=8 rows of reuse that is 64
// B/cyc/CU == the L1/LDS data-path ceiling (same ceiling whichever path).
// Fix: R=16 rows/lane (demand 32 B/cyc), lane owns 16r x 2c (acc=32),
// block = 8 waves x 128 cols = 1024 cols x 16 rows. A staged once/rowtile
// into 20.7KB LDS, read as wave-uniform ds_read_b128 broadcasts (16B,
// conflict-free, lgkmcnt -> decoupled from B's vmcnt prefetch). No merge
// (1 thread owns a column for ALL h) -> barrier-free k-loop.
#define BM 16         // h rows per block tile (shared by all 8 waves)
#define LDR 324       // Alds row stride in floats (1296 B, 16B-aligned)
#define NRT 263       // ceil(H_DIM / BM)
#define NG  80        // 4-k groups covering k=0..319 (tail k=320 separate)

typedef float v4f __attribute__((ext_vector_type(4)));
typedef float v2f __attribute__((ext_vector_type(2)));

__device__ __forceinline__ void ins3(float v, int i,
                                     float& v0, float& v1, float& v2,
                                     int& i0, int& i1, int& i2) {
  // strict '>' keeps earlier (smaller-h) entries ahead on ties == lax.top_k
  if (v > v0)      { v2 = v1; i2 = i1; v1 = v0; i1 = i0; v0 = v; i0 = i; }
  else if (v > v1) { v2 = v1; i2 = i1; v1 = v;  i1 = i; }
  else if (v > v2) { v2 = v;  i2 = i; }
}

// load one 4-k B group (4 k-rows x 2 cols/lane) into 4 named v2f regs
#define LOADB(B0, B1, B2, B3, g) do {                                  \
    const float* _p = pB + (size_t)((g) * 4) * T_DIM;                  \
    B0 = *(const v2f*)(_p);                                            \
    B1 = *(const v2f*)(_p + T_DIM);                                    \
    B2 = *(const v2f*)(_p + 2 * T_DIM);                                \
    B3 = *(const v2f*)(_p + 3 * T_DIM);                                \
  } while (0)

// FMA one 4-k group: A via wave-uniform LDS broadcast, k ascending per acc
#define FMAG(B0, B1, B2, B3, g) do {                                   \
    _Pragma("unroll") for (int r = 0; r < 16; ++r) {                   \
      const v4f Ar = *(const v4f*)(&Alds[r * LDR + (g) * 4]);          \
      _Pragma("unroll") for (int c = 0; c < 2; ++c) {                  \
        acc[r][c] = fmaf(Ar[0], B0[c], acc[r][c]);                     \
        acc[r][c] = fmaf(Ar[1], B1[c], acc[r][c]);                     \
        acc[r][c] = fmaf(Ar[2], B2[c], acc[r][c]);                     \
        acc[r][c] = fmaf(Ar[3], B3[c], acc[r][c]);                     \
      }                                                                \
    }                                                                  \
  } while (0)

// K1: fused fp32 GEMM (nominee = integral_m @ mag[bc]) + running top-3 over h.
__global__ __launch_bounds__(512)
void hi_k1_gemm_top3(const float* __restrict__ mag,
                     const float* __restrict__ im,
                     float* __restrict__ wv, int* __restrict__ wi,
                     int nsplit) {
  const int tid  = threadIdx.x;
  const int lane = tid & 63;
  const int tg   = tid >> 6;      // wave = t-group 0..7
  const int bc = blockIdx.y;
  const int sp = blockIdx.x;
  const int rt_begin = (sp * NRT) / nsplit;
  const int rt_end   = ((sp + 1) * NRT) / nsplit;
  const int tcol0 = tg * 128 + lane * 2;   // this thread's first t column

  __shared__ __align__(16) float Alds[BM * LDR];   // 20.7 KB, shared rows

  const float* magbc = mag + (size_t)bc * F_DIM * T_DIM;
  const float* pB = magbc + tcol0;
  // (cols 1000..1023 read in-bounds garbage from the next k-row; those
  //  threads' results are discarded at store time. max addr 319*1000+1022
  //  < 321*1000. k=320 tail is guarded.)

  float gv[2][3], gi_f; int gi[2][3];
#pragma unroll
  for (int c = 0; c < 2; ++c)
#pragma unroll
    for (int j = 0; j < 3; ++j) { gv[c][j] = -INFINITY; gi[c][j] = 0; }
  (void)gi_f;

  for (int rt = rt_begin; rt < rt_end; ++rt) {
    const int h0 = rt * BM;

    // stage A: 16 rows x 321 floats; 32 threads/row, coalesced 128B chunks
    {
      const int r = tid >> 5, i0 = tid & 31;
      int gh = h0 + r;
      if (gh >= H_DIM) gh = H_DIM - 1;        // dup row, masked at top-3
      const float* srow = im + (size_t)gh * F_DIM;
      for (int j = i0; j < F_DIM; j += 32) Alds[r * LDR + j] = srow[j];
    }
    __syncthreads();

    float acc[16][2];
#pragma unroll
    for (int r = 0; r < 16; ++r) { acc[r][0] = 0.f; acc[r][1] = 0.f; }

    v2f Bc0, Bc1, Bc2, Bc3, Bn0, Bn1, Bn2, Bn3;
    LOADB(Bc0, Bc1, Bc2, Bc3, 0);

    // 40 double-steps over g=0..79; B reg-dbuf 1 group ahead (vmcnt),
    // A broadcast from LDS (lgkmcnt) -- pipelines are independent, no
    // barriers, waves free-run.
#pragma unroll 1
    for (int gs = 0; gs < NG / 2; ++gs) {
      const int ge = 2 * gs, go = 2 * gs + 1;
      LOADB(Bn0, Bn1, Bn2, Bn3, go);
      FMAG(Bc0, Bc1, Bc2, Bc3, ge);
      if (ge + 2 < NG) LOADB(Bc0, Bc1, Bc2, Bc3, ge + 2);
      FMAG(Bn0, Bn1, Bn2, Bn3, go);
    }

    // K tail: k = 320, guarded B, uniform A from Alds
    {
      float bt[2];
#pragma unroll
      for (int c = 0; c < 2; ++c) {
        int gt = tcol0 + c;
        bt[c] = (gt < T_DIM) ? magbc[(size_t)(F_DIM - 1) * T_DIM + gt] : 0.f;
      }
#pragma unroll
      for (int r = 0; r < 16; ++r) {
        float av = Alds[r * LDR + (F_DIM - 1)];
        acc[r][0] = fmaf(av, bt[0], acc[r][0]);
        acc[r][1] = fmaf(av, bt[1], acc[r][1]);
      }
    }

    // local top-3 over this rowtile's 16 rows (h ascending), then merge
    // into the running per-thread list (rowtiles ascend in h -> order ok)
#pragma unroll
    for (int c = 0; c < 2; ++c) {
      float v0 = -INFINITY, v1 = -INFINITY, v2 = -INFINITY;
      int   i0 = 0, i1 = 0, i2 = 0;
#pragma unroll
      for (int r = 0; r < 16; ++r) {
        int gh = h0 + r;
        float v = (gh < H_DIM) ? acc[r][c] : -INFINITY;
        ins3(v, gh, v0, v1, v2, i0, i1, i2);
      }
      ins3(v0, i0, gv[c][0], gv[c][1], gv[c][2], gi[c][0], gi[c][1], gi[c][2]);
      ins3(v1, i1, gv[c][0], gv[c][1], gv[c][2], gi[c][0], gi[c][1], gi[c][2]);
      ins3(v2, i2, gv[c][0], gv[c][1], gv[c][2], gi[c][0], gi[c][1], gi[c][2]);
    }
    __syncthreads();   // Alds reads done before next rowtile restages
  }

#pragma unroll
  for (int c = 0; c < 2; ++c) {
    int t = tcol0 + c;
    if (t < T_DIM) {
      size_t base = ((size_t)(bc * nsplit + sp) * KTOP) * T_DIM + t;
      wv[base]             = gv[c][0];
      wv[base + T_DIM]     = gv[c][1];
      wv[base + 2 * T_DIM] = gv[c][2];
      wi[base]             = gi[c][0];
      wi[base + T_DIM]     = gi[c][1];
      wi[base + 2 * T_DIM] = gi[c][2];
    }
  }
}

// K3: merge the nsplit partial top-3 lists, causal-pool the indices, gather
// harmonic_loc rows, sum over K, threshold, write (B,C,F,T) coalesced.
__global__ __launch_bounds__(256, 4)
void hi_k3_pool_gather(const float* __restrict__ wv, const int* __restrict__ wi,
                       const float* __restrict__ hl, float* __restrict__ out,
                       int nsplit) {
  const int tid = threadIdx.x;
  const int t0 = blockIdx.x * 64;
  const int bc = blockIdx.y;

  __shared__ float pos_lds[66 * KTOP];   // t0-2 .. t0+63
  __shared__ int   rows[64 * KTOP];
  __shared__ float S[64 * 65];           // [t_local][f_chunk] transpose buffer

  if (tid < 66) {
    int t = t0 - 2 + tid;
    float p0 = PADV, p1 = PADV, p2 = PADV;
    if (t >= 0 && t < T_DIM) {
      float v0 = -INFINITY, v1 = -INFINITY, v2 = -INFINITY;
      int i0 = 0, i1 = 0, i2 = 0;
      for (int sp = 0; sp < nsplit; ++sp)        // ascending h ranges
        for (int j = 0; j < KTOP; ++j) {         // descending values
          size_t idx = ((size_t)(bc * nsplit + sp) * KTOP + j) * T_DIM + t;
          ins3(wv[idx], wi[idx], v0, v1, v2, i0, i1, i2);
        }
      p0 = (float)i0; p1 = (float)i1; p2 = (float)i2;
    }
    pos_lds[tid * KTOP + 0] = p0;
    pos_lds[tid * KTOP + 1] = p1;
    pos_lds[tid * KTOP + 2] = p2;
  }
  __syncthreads();
  if (tid < 64) {
#pragma unroll
    for (int k = 0; k < KTOP; ++k) {
      float s = (pos_lds[tid * KTOP + k] + pos_lds[(tid + 1) * KTOP + k])
                + pos_lds[(tid + 2) * KTOP + k];
      rows[tid * KTOP + k] = (int)(s / 3.0f);   // matches ref fp32 /3 + int cast
    }
  }
  __syncthreads();

  const int w = tid >> 6, lane = tid & 63;
  for (int fc = 0; fc < 6; ++fc) {
    const int f0 = fc * 64;
    for (int i = 0; i < 16; ++i) {
      int tl = w * 16 + i;
      int r0 = rows[tl * KTOP + 0];
      int r1 = rows[tl * KTOP + 1];
      int r2 = rows[tl * KTOP + 2];
      int f = f0 + lane;
      float s = 0.f;
      if (f < F_DIM)
        s = (hl[(size_t)r0 * F_DIM + f] + hl[(size_t)r1 * F_DIM + f])
            + hl[(size_t)r2 * F_DIM + f];
      S[tl * 65 + lane] = s;
    }
    __syncthreads();
#pragma unroll
    for (int i = 0; i < 16; ++i) {
      int e = tid + 256 * i;
      int fl = e >> 6, tl = e & 63;
      int f = f0 + fl, t = t0 + tl;
      if (f < F_DIM && t < T_DIM)
        out[((size_t)bc * F_DIM + f) * T_DIM + t] = (S[tl * 65 + fl] > 0.f) ? 1.f : 0.f;
    }
    __syncthreads();
  }
}

extern "C" void kernel_launch(void* const* d_in, const int* in_sizes, int n_in,
                              void* d_out, int out_size, void* d_ws, size_t ws_size,
                              hipStream_t stream) {
  const float* mag = (const float*)d_in[0];   // (8,2,321,1000)
  const float* im  = (const float*)d_in[1];   // (4200,321)
  const float* hl  = (const float*)d_in[2];   // (4200,321)
  float* out = (float*)d_out;                 // (8,2,321,1000)

  // pick largest nsplit the workspace can hold
  int nsplit = 16;
  if (ws_size >= (size_t)NBC * 64 * KTOP * T_DIM * 8) nsplit = 64;       // 24.6 MB
  else if (ws_size >= (size_t)NBC * 32 * KTOP * T_DIM * 8) nsplit = 32;  // 12.3 MB
  float* wv = (float*)d_ws;
  int*   wi = (int*)d_ws + (size_t)NBC * nsplit * KTOP * T_DIM;

  dim3 g1(nsplit, NBC);        // nsplit x 16 blocks of 512 threads
  hipLaunchKernelGGL(hi_k1_gemm_top3, g1, dim3(512), 0, stream, mag, im, wv, wi, nsplit);

  dim3 g3((T_DIM + 63) / 64, NBC);               // 16 x 16 = 256 blocks
  hipLaunchKernelGGL(hi_k3_pool_gather, g3, dim3(256), 0, stream, wv, wi, hl, out, nsplit);
}

// Round 22
// 909.609 us; speedup vs baseline: 1.5190x; 1.5190x over previous
//
#include <hip/hip_runtime.h>
#include <math.h>

// Problem constants
#define F_DIM 321
#define H_DIM 4200
#define T_DIM 1000
#define NBC   16      // B*C = 8*2
#define KTOP  3
#define PADV  1e-8f

// r22 = r20 (best, 938us) + A register double-buffer. r20's FMAG loaded 32
// uniform A values per group with NO prefetch -> ~200-350cyc scalar-load
// stall per 256cyc FMA block -> VALUBusy 42% (measured 40.7). B already had
// a reg-dbuf; A now gets the same treatment (Ac/An named arrays, static
// indexing). r21's LDS-broadcast A is abandoned (LDS pipe oversubscribed,
// 1382us). Zero-LDS, zero-barrier main loop retained.
#define BM 32         // h rows per block tile (4 waves x 8)
#define BN 256        // t cols per block tile (64 lanes x 4)
#define NRT 132       // ceil(H_DIM / BM)
#define NG  80        // 4-k groups covering k=0..319 (tail k=320 separate)
#define NTT 4         // ceil(T_DIM / BN)

typedef float v4f __attribute__((ext_vector_type(4)));

__device__ __forceinline__ void ins3(float v, int i,
                                     float& v0, float& v1, float& v2,
                                     int& i0, int& i1, int& i2) {
  // strict '>' keeps earlier (smaller-h) entries ahead on ties == lax.top_k
  if (v > v0)      { v2 = v1; i2 = i1; v1 = v0; i1 = i0; v0 = v; i0 = i; }
  else if (v > v1) { v2 = v1; i2 = i1; v1 = v;  i1 = i; }
  else if (v > v2) { v2 = v;  i2 = i; }
}

// load one 4-k B group (4 rows x 4 cols/lane) into 4 named v4f regs
#define LOADB(B0, B1, B2, B3, g) do {                                  \
    const float* _p = pB + (size_t)((g) * 4) * T_DIM;                  \
    B0 = *(const v4f*)(_p);                                            \
    B1 = *(const v4f*)(_p + T_DIM);                                    \
    B2 = *(const v4f*)(_p + 2 * T_DIM);                                \
    B3 = *(const v4f*)(_p + 3 * T_DIM);                                \
  } while (0)

// load one 4-k A group (8 rows x 4 k, wave-uniform) into named array D
#define LOADA(D, g) do {                                               \
    _Pragma("unroll") for (int r = 0; r < 8; ++r)                      \
      _Pragma("unroll") for (int q = 0; q < 4; ++q)                    \
        D[r][q] = im[ab[r] + (g) * 4 + q];                             \
  } while (0)

// FMA one 4-k group from pre-loaded A array (k ascending per acc element)
#define FMAG(B0, B1, B2, B3, A) do {                                   \
    _Pragma("unroll") for (int r = 0; r < 8; ++r)                      \
      _Pragma("unroll") for (int c = 0; c < 4; ++c) {                  \
        acc[r][c] = fmaf(A[r][0], B0[c], acc[r][c]);                   \
        acc[r][c] = fmaf(A[r][1], B1[c], acc[r][c]);                   \
        acc[r][c] = fmaf(A[r][2], B2[c], acc[r][c]);                   \
        acc[r][c] = fmaf(A[r][3], B3[c], acc[r][c]);                   \
      }                                                                \
  } while (0)

// K1: fused fp32 GEMM (nominee = integral_m @ mag[bc]) + running top-3 over h.
__global__ __launch_bounds__(256)
void hi_k1_gemm_top3(const float* __restrict__ mag,
                     const float* __restrict__ im,
                     float* __restrict__ wv, int* __restrict__ wi,
                     int nsplit) {
  const int tid  = threadIdx.x;
  const int lane = tid & 63;
  const int w    = tid >> 6;      // wave index 0..3
  const int t0 = blockIdx.x * BN;
  const int bc = blockIdx.y;
  const int sp = blockIdx.z;
  const int rt_begin = (sp * NRT) / nsplit;
  const int rt_end   = ((sp + 1) * NRT) / nsplit;

  __shared__ float mv[4 * BN * KTOP];   // merge scratch only (12 KB)
  __shared__ int   mi[4 * BN * KTOP];   // (12 KB)

  const float* magbc = mag + (size_t)bc * F_DIM * T_DIM;
  const float* pB = magbc + t0 + lane * 4;   // per-lane B column base
  // (t overrun of the last t-tile reads into the next k-row: in-bounds for
  //  k<=319, and those columns are discarded at store time -- r19-verified)

  float gv0 = -INFINITY, gv1 = -INFINITY, gv2 = -INFINITY;
  int   gi0 = 0, gi1 = 0, gi2 = 0;

  for (int rt = rt_begin; rt < rt_end; ++rt) {
    const int h0 = rt * BM;
    // wave-uniform row bases (SGPR); clamp dups masked at top-3 (as r19)
    int ab[8];
#pragma unroll
    for (int r = 0; r < 8; ++r) {
      int gh = h0 + w * 8 + r;
      if (gh >= H_DIM) gh = H_DIM - 1;
      ab[r] = __builtin_amdgcn_readfirstlane(gh * F_DIM);
    }

    float acc[8][4];
#pragma unroll
    for (int r = 0; r < 8; ++r)
#pragma unroll
      for (int c = 0; c < 4; ++c) acc[r][c] = 0.f;

    float Ac[8][4], An[8][4];
    v4f Bc0, Bc1, Bc2, Bc3, Bn0, Bn1, Bn2, Bn3;
    LOADA(Ac, 0);
    LOADB(Bc0, Bc1, Bc2, Bc3, 0);

    // 40 double-steps cover g=0..79 (k=0..319). Both operands register-
    // double-buffered one group ahead; no LDS, no barriers; per-wave
    // waitcnts overlap the other buffer's 256-cycle FMA block.
#pragma unroll 1
    for (int gs = 0; gs < NG / 2; ++gs) {
      const int ge = 2 * gs, go = 2 * gs + 1;
      LOADA(An, go);
      LOADB(Bn0, Bn1, Bn2, Bn3, go);          // go <= 79 always
      FMAG(Bc0, Bc1, Bc2, Bc3, Ac);
      if (ge + 2 < NG) {
        LOADA(Ac, ge + 2);
        LOADB(Bc0, Bc1, Bc2, Bc3, ge + 2);
      }
      FMAG(Bn0, Bn1, Bn2, Bn3, An);
    }

    // K tail: k = 320 (single column), guarded loads
    {
      float bt[4];
#pragma unroll
      for (int c = 0; c < 4; ++c) {
        int gt = t0 + lane * 4 + c;
        bt[c] = (gt < T_DIM) ? magbc[(size_t)(F_DIM - 1) * T_DIM + gt] : 0.f;
      }
#pragma unroll
      for (int r = 0; r < 8; ++r) {
        float av = im[ab[r] + (F_DIM - 1)];
#pragma unroll
        for (int c = 0; c < 4; ++c) acc[r][c] = fmaf(av, bt[c], acc[r][c]);
      }
    }

    // thread-local top-3 per column over own 8 rows (h ascending); wave
    // bands ascend in w, so cross-wave merge preserves lax.top_k tie order.
#pragma unroll
    for (int c = 0; c < 4; ++c) {
      const int col = lane * 4 + c;
      float v0 = -INFINITY, v1 = -INFINITY, v2 = -INFINITY;
      int   i0 = 0, i1 = 0, i2 = 0;
#pragma unroll
      for (int r = 0; r < 8; ++r) {
        int gh = h0 + w * 8 + r;
        float v = (gh < H_DIM) ? acc[r][c] : -INFINITY;
        ins3(v, gh, v0, v1, v2, i0, i1, i2);
      }
      mv[(w * BN + col) * 3 + 0] = v0;
      mv[(w * BN + col) * 3 + 1] = v1;
      mv[(w * BN + col) * 3 + 2] = v2;
      mi[(w * BN + col) * 3 + 0] = i0;
      mi[(w * BN + col) * 3 + 1] = i1;
      mi[(w * BN + col) * 3 + 2] = i2;
    }
    __syncthreads();
    // thread tid owns column tid; merge the 4 wave lists (ascending h)
    {
      const int col = tid;
#pragma unroll
      for (int ww = 0; ww < 4; ++ww)
#pragma unroll
        for (int j = 0; j < 3; ++j) {
          float v = mv[(ww * BN + col) * 3 + j];
          int   i = mi[(ww * BN + col) * 3 + j];
          ins3(v, i, gv0, gv1, gv2, gi0, gi1, gi2);
        }
    }
    __syncthreads();   // merge reads done before next rowtile overwrites
  }

  {
    int t = t0 + tid;
    if (t < T_DIM) {
      size_t base = ((size_t)(bc * nsplit + sp) * KTOP) * T_DIM + t;
      wv[base]             = gv0;
      wv[base + T_DIM]     = gv1;
      wv[base + 2 * T_DIM] = gv2;
      wi[base]             = gi0;
      wi[base + T_DIM]     = gi1;
      wi[base + 2 * T_DIM] = gi2;
    }
  }
}

// K3: merge the nsplit partial top-3 lists, causal-pool the indices, gather
// harmonic_loc rows, sum over K, threshold, write (B,C,F,T) coalesced.
__global__ __launch_bounds__(256, 4)
void hi_k3_pool_gather(const float* __restrict__ wv, const int* __restrict__ wi,
                       const float* __restrict__ hl, float* __restrict__ out,
                       int nsplit) {
  const int tid = threadIdx.x;
  const int t0 = blockIdx.x * 64;
  const int bc = blockIdx.y;

  __shared__ float pos_lds[66 * KTOP];   // t0-2 .. t0+63
  __shared__ int   rows[64 * KTOP];
  __shared__ float S[64 * 65];           // [t_local][f_chunk] transpose buffer

  if (tid < 66) {
    int t = t0 - 2 + tid;
    float p0 = PADV, p1 = PADV, p2 = PADV;
    if (t >= 0 && t < T_DIM) {
      float v0 = -INFINITY, v1 = -INFINITY, v2 = -INFINITY;
      int i0 = 0, i1 = 0, i2 = 0;
      for (int sp = 0; sp < nsplit; ++sp)        // ascending h ranges
        for (int j = 0; j < KTOP; ++j) {         // descending values
          size_t idx = ((size_t)(bc * nsplit + sp) * KTOP + j) * T_DIM + t;
          ins3(wv[idx], wi[idx], v0, v1, v2, i0, i1, i2);
        }
      p0 = (float)i0; p1 = (float)i1; p2 = (float)i2;
    }
    pos_lds[tid * KTOP + 0] = p0;
    pos_lds[tid * KTOP + 1] = p1;
    pos_lds[tid * KTOP + 2] = p2;
  }
  __syncthreads();
  if (tid < 64) {
#pragma unroll
    for (int k = 0; k < KTOP; ++k) {
      float s = (pos_lds[tid * KTOP + k] + pos_lds[(tid + 1) * KTOP + k])
                + pos_lds[(tid + 2) * KTOP + k];
      rows[tid * KTOP + k] = (int)(s / 3.0f);   // matches ref fp32 /3 + int cast
    }
  }
  __syncthreads();

  const int w = tid >> 6, lane = tid & 63;
  for (int fc = 0; fc < 6; ++fc) {
    const int f0 = fc * 64;
    for (int i = 0; i < 16; ++i) {
      int tl = w * 16 + i;
      int r0 = rows[tl * KTOP + 0];
      int r1 = rows[tl * KTOP + 1];
      int r2 = rows[tl * KTOP + 2];
      int f = f0 + lane;
      float s = 0.f;
      if (f < F_DIM)
        s = (hl[(size_t)r0 * F_DIM + f] + hl[(size_t)r1 * F_DIM + f])
            + hl[(size_t)r2 * F_DIM + f];
      S[tl * 65 + lane] = s;
    }
    __syncthreads();
#pragma unroll
    for (int i = 0; i < 16; ++i) {
      int e = tid + 256 * i;
      int fl = e >> 6, tl = e & 63;
      int f = f0 + fl, t = t0 + tl;
      if (f < F_DIM && t < T_DIM)
        out[((size_t)bc * F_DIM + f) * T_DIM + t] = (S[tl * 65 + fl] > 0.f) ? 1.f : 0.f;
    }
    __syncthreads();
  }
}

extern "C" void kernel_launch(void* const* d_in, const int* in_sizes, int n_in,
                              void* d_out, int out_size, void* d_ws, size_t ws_size,
                              hipStream_t stream) {
  const float* mag = (const float*)d_in[0];   // (8,2,321,1000)
  const float* im  = (const float*)d_in[1];   // (4200,321)
  const float* hl  = (const float*)d_in[2];   // (4200,321)
  float* out = (float*)d_out;                 // (8,2,321,1000)

  // pick largest nsplit the workspace can hold (8 is known-safe: 3.07 MB)
  int nsplit = 8;
  if (ws_size >= (size_t)NBC * 32 * KTOP * T_DIM * 8) nsplit = 32;       // 12.3 MB
  else if (ws_size >= (size_t)NBC * 16 * KTOP * T_DIM * 8) nsplit = 16;  // 6.1 MB
  float* wv = (float*)d_ws;
  int*   wi = (int*)d_ws + (size_t)NBC * nsplit * KTOP * T_DIM;

  dim3 g1(NTT, NBC, nsplit);   // 4 x 16 x nsplit blocks
  hipLaunchKernelGGL(hi_k1_gemm_top3, g1, dim3(256), 0, stream, mag, im, wv, wi, nsplit);

  dim3 g3((T_DIM + 63) / 64, NBC);               // 16 x 16 = 256 blocks
  hipLaunchKernelGGL(hi_k3_pool_gather, g3, dim3(256), 0, stream, wv, wi, hl, out, nsplit);
}